// Round 3
// baseline (2480.660 us; speedup 1.0000x reference)
//
#include <hip/hip_runtime.h>
#include <stdint.h>

// GeneralConv fused pipeline for MI355X (gfx950) — barrier-free wave-tile version.
// CSR path: hist/scan/fill -> bond_v3 (per-wave 32-edge tiles, no s_barrier,
// A gathered straight into MFMA fragment layout, B from L2-hot packed weights)
// -> streaming segment-mean -> node_v3 (same structure + fused LayerNorm).
// Fallback path (ws too small): old atomic bond kernel.

#define NN 50000
#define NE 800000
#define NPART 196   // ceil(NN/256)

typedef short bf16x8 __attribute__((ext_vector_type(8)));
typedef float f32x4 __attribute__((ext_vector_type(4)));

#define MFMA16(a, b, c) __builtin_amdgcn_mfma_f32_16x16x32_bf16((a), (b), (c), 0, 0, 0)

union U8 { uint4 q; bf16x8 v; };

__device__ __forceinline__ uint32_t f2bf(float f) {
  union { float f; uint32_t u; } x; x.f = f;
  uint32_t u = x.u;
  u += 0x7FFFu + ((u >> 16) & 1u);   // RNE
  return u >> 16;
}
__device__ __forceinline__ float bf2f(uint32_t lo16) {
  union { uint32_t u; float f; } x; x.u = lo16 << 16; return x.f;
}
__device__ __forceinline__ float sigm(float x) { return 1.0f / (1.0f + __expf(-x)); }

__device__ __forceinline__ bf16x8 pack8(float4 a, float4 b) {
  U8 u;
  u.q.x = f2bf(a.x) | (f2bf(a.y) << 16);
  u.q.y = f2bf(a.z) | (f2bf(a.w) << 16);
  u.q.z = f2bf(b.x) | (f2bf(b.y) << 16);
  u.q.w = f2bf(b.z) | (f2bf(b.w) << 16);
  return u.v;
}
__device__ __forceinline__ bf16x8 ldb(const unsigned short* p) {
  U8 u; u.q = *(const uint4*)p; return u.v;
}

// Transpose fp32 W[K][128] -> bf16 WT[128][Kpad], zero-padded rows k>=K.
__global__ void pack_wT(const float* __restrict__ W, unsigned short* __restrict__ WT,
                        int K, int Kpad) {
  int id = blockIdx.x * 256 + threadIdx.x;
  if (id >= 128 * Kpad) return;
  int h = id / Kpad, k = id - h * Kpad;
  WT[id] = f2bf(k < K ? W[k * 128 + h] : 0.0f);
}

// ---------------- CSR build ----------------
__global__ __launch_bounds__(256) void hist_kernel(const int* __restrict__ ei,
                                                   int* __restrict__ cnt) {
  int e = blockIdx.x * 256 + threadIdx.x;
  if (e < NE) atomicAdd(&cnt[ei[e]], 1);
}

__global__ __launch_bounds__(256) void scan1(const int* __restrict__ cnt,
                                             int* __restrict__ partials) {
  int t = threadIdx.x;
  int i = blockIdx.x * 256 + t;
  int v = (i < NN) ? cnt[i] : 0;
#pragma unroll
  for (int d = 1; d < 64; d <<= 1) v += __shfl_xor(v, d, 64);
  __shared__ int ws4[4];
  if ((t & 63) == 0) ws4[t >> 6] = v;
  __syncthreads();
  if (t == 0) partials[blockIdx.x] = ws4[0] + ws4[1] + ws4[2] + ws4[3];
}

__global__ __launch_bounds__(256) void scan2(int* __restrict__ partials,
                                             int* __restrict__ offsets) {
  int t = threadIdx.x;
  int v = (t < NPART) ? partials[t] : 0;
  int incl = v;
#pragma unroll
  for (int d = 1; d < 64; d <<= 1) {
    int u = __shfl_up(incl, d, 64);
    if ((t & 63) >= d) incl += u;
  }
  __shared__ int wsum[4];
  if ((t & 63) == 63) wsum[t >> 6] = incl;
  __syncthreads();
  int add = 0;
  for (int w = 0; w < (t >> 6); ++w) add += wsum[w];
  incl += add;
  if (t < NPART) partials[t] = incl - v;   // exclusive block offsets
  if (t == 255) offsets[NN] = incl;        // total = NE
}

__global__ __launch_bounds__(256) void scan3(const int* __restrict__ cnt,
                                             const int* __restrict__ partials,
                                             int* __restrict__ offsets,
                                             int* __restrict__ cursor) {
  int t = threadIdx.x;
  int i = blockIdx.x * 256 + t;
  int v = (i < NN) ? cnt[i] : 0;
  int incl = v;
#pragma unroll
  for (int d = 1; d < 64; d <<= 1) {
    int u = __shfl_up(incl, d, 64);
    if ((t & 63) >= d) incl += u;
  }
  __shared__ int wsum[4];
  if ((t & 63) == 63) wsum[t >> 6] = incl;
  __syncthreads();
  int add = partials[blockIdx.x];
  for (int w = 0; w < (t >> 6); ++w) add += wsum[w];
  int excl = incl - v + add;
  if (i < NN) { offsets[i] = excl; cursor[i] = excl; }
}

__global__ __launch_bounds__(256) void fill_kernel(const int* __restrict__ ei,
                                                   int* __restrict__ cursor,
                                                   int* __restrict__ eidS,
                                                   int* __restrict__ srcS,
                                                   int* __restrict__ dstS) {
  int e = blockIdx.x * 256 + threadIdx.x;
  if (e >= NE) return;
  int s = ei[e], d = ei[NE + e];
  int pos = atomicAdd(&cursor[s], 1);
  eidS[pos] = e; srcS[pos] = s; dstS[pos] = d;
}

// ---------------------------------------------------------------------------
// bond_v3: barrier-free. One wave == one 32-edge tile (grid-stride).
// Layer 1: A gathered global->regs in fragment layout; B frags from global WT.
// Layer 2: per-wave private LDS slice (8 KB) for the H transpose; no s_barrier.
// Output: bf16 concat row at CSR slot via LDS transpose + coalesced uint4.
// ---------------------------------------------------------------------------
__global__ __launch_bounds__(256, 2) void bond_v3(
    const float* __restrict__ node_inp, const float* __restrict__ edge_feat,
    const int* __restrict__ srcS, const int* __restrict__ dstS,
    const int* __restrict__ eidS,
    const unsigned short* __restrict__ Wm0T, const unsigned short* __restrict__ Wg0T,
    const unsigned short* __restrict__ Wm1T, const unsigned short* __restrict__ Wg1T,
    const float* __restrict__ bm0, const float* __restrict__ bg0,
    const float* __restrict__ bm1, const float* __restrict__ bg1,
    unsigned short* __restrict__ concat) {
  __shared__ char smem[32768];
  const int t = threadIdx.x;
  const int lane = t & 63;
  const int wv = t >> 6;
  const int lg = lane >> 4;
  const int lr = lane & 15;
  char* hs = smem + wv * 8192;   // private per-wave slice [32 rows][128 cols] bf16

  // loop-invariant per-lane bias fragments
  float b0m[8], b0g[8], b1m[8], b1g[8];
#pragma unroll
  for (int nf = 0; nf < 8; ++nf) {
    b0m[nf] = bm0[nf * 16 + lr];
    b0g[nf] = bg0[nf * 16 + lr];
    b1m[nf] = bm1[nf * 16 + lr];
    b1g[nf] = bg1[nf * 16 + lr];
  }

  const int NT = NE / 32;
  for (int tile = blockIdx.x * 4 + wv; tile < NT; tile += gridDim.x * 4) {
    const int tbase = tile * 32;
    const int rlo = tbase + lr, rhi = rlo + 16;
    const float* blo[3] = {node_inp + (size_t)srcS[rlo] * 128,
                           node_inp + (size_t)dstS[rlo] * 128,
                           edge_feat + (size_t)eidS[rlo] * 128};
    const float* bhi[3] = {node_inp + (size_t)srcS[rhi] * 128,
                           node_inp + (size_t)dstS[rhi] * 128,
                           edge_feat + (size_t)eidS[rhi] * 128};

    f32x4 accm[2][8] = {};
    f32x4 accg[2][8] = {};

#pragma unroll
    for (int sel = 0; sel < 3; ++sel) {
      const float* plo = blo[sel] + lg * 8;
      const float* phi = bhi[sel] + lg * 8;
#pragma unroll 2
      for (int kq = 0; kq < 4; ++kq) {
        const int kc = sel * 4 + kq;
        float4 x0 = ((const float4*)(plo + kq * 32))[0];
        float4 x1 = ((const float4*)(plo + kq * 32))[1];
        float4 y0 = ((const float4*)(phi + kq * 32))[0];
        float4 y1 = ((const float4*)(phi + kq * 32))[1];
        bf16x8 alo = pack8(x0, x1);
        bf16x8 ahi = pack8(y0, y1);
        const int kof = kc * 32 + lg * 8;
#pragma unroll
        for (int nf = 0; nf < 8; ++nf) {
          const int wrow = (nf * 16 + lr) * 384 + kof;
          bf16x8 bm = ldb(Wm0T + wrow);
          accm[0][nf] = MFMA16(alo, bm, accm[0][nf]);
          accm[1][nf] = MFMA16(ahi, bm, accm[1][nf]);
          bf16x8 bg = ldb(Wg0T + wrow);
          accg[0][nf] = MFMA16(alo, bg, accg[0][nf]);
          accg[1][nf] = MFMA16(ahi, bg, accg[1][nf]);
        }
      }
    }

    // ---- layer 2, branch m: silu -> private LDS (swizzled) -> MFMA ----
    f32x4 acc2m[2][8] = {};
    f32x4 acc2g[2][8] = {};
#pragma unroll
    for (int mf = 0; mf < 2; ++mf)
#pragma unroll
      for (int nf = 0; nf < 8; ++nf)
#pragma unroll
        for (int r = 0; r < 4; ++r) {
          float h = accm[mf][nf][r] + b0m[nf];
          h = h * sigm(h);
          int row = mf * 16 + lg * 4 + r;
          *(unsigned short*)(hs + ((row * 256 + (nf * 16 + lr) * 2) ^ ((row & 7) << 4))) =
              (unsigned short)f2bf(h);
        }
#pragma unroll
    for (int kc = 0; kc < 4; ++kc) {
      const int kb = (kc * 32 + lg * 8) * 2;
      bf16x8 alo = *(const bf16x8*)(hs + ((lr * 256 + kb) ^ ((lr & 7) << 4)));
      bf16x8 ahi = *(const bf16x8*)(hs + (((lr + 16) * 256 + kb) ^ ((lr & 7) << 4)));
#pragma unroll
      for (int nf = 0; nf < 8; ++nf) {
        bf16x8 b = ldb(Wm1T + (nf * 16 + lr) * 128 + kc * 32 + lg * 8);
        acc2m[0][nf] = MFMA16(alo, b, acc2m[0][nf]);
        acc2m[1][nf] = MFMA16(ahi, b, acc2m[1][nf]);
      }
    }

    // ---- layer 2, branch g ----
#pragma unroll
    for (int mf = 0; mf < 2; ++mf)
#pragma unroll
      for (int nf = 0; nf < 8; ++nf)
#pragma unroll
        for (int r = 0; r < 4; ++r) {
          float h = accg[mf][nf][r] + b0g[nf];
          h = h * sigm(h);
          int row = mf * 16 + lg * 4 + r;
          *(unsigned short*)(hs + ((row * 256 + (nf * 16 + lr) * 2) ^ ((row & 7) << 4))) =
              (unsigned short)f2bf(h);
        }
#pragma unroll
    for (int kc = 0; kc < 4; ++kc) {
      const int kb = (kc * 32 + lg * 8) * 2;
      bf16x8 alo = *(const bf16x8*)(hs + ((lr * 256 + kb) ^ ((lr & 7) << 4)));
      bf16x8 ahi = *(const bf16x8*)(hs + (((lr + 16) * 256 + kb) ^ ((lr & 7) << 4)));
#pragma unroll
      for (int nf = 0; nf < 8; ++nf) {
        bf16x8 b = ldb(Wg1T + (nf * 16 + lr) * 128 + kc * 32 + lg * 8);
        acc2g[0][nf] = MFMA16(alo, b, acc2g[0][nf]);
        acc2g[1][nf] = MFMA16(ahi, b, acc2g[1][nf]);
      }
    }

    // ---- combine m * sigmoid(g) -> LDS -> coalesced bf16 row stores ----
#pragma unroll
    for (int mf = 0; mf < 2; ++mf)
#pragma unroll
      for (int nf = 0; nf < 8; ++nf)
#pragma unroll
        for (int r = 0; r < 4; ++r) {
          float mv = acc2m[mf][nf][r] + b1m[nf];
          float gv = sigm(acc2g[mf][nf][r] + b1g[nf]);
          int row = mf * 16 + lg * 4 + r;
          *(unsigned short*)(hs + ((row * 256 + (nf * 16 + lr) * 2) ^ ((row & 7) << 4))) =
              (unsigned short)f2bf(mv * gv);
        }
#pragma unroll
    for (int it = 0; it < 8; ++it) {
      int row = it * 4 + lg;
      uint4 v = *(const uint4*)(hs + ((row * 256 + lr * 16) ^ ((row & 7) << 4)));
      *(uint4*)(concat + (size_t)(tbase + row) * 128 + lr * 8) = v;
    }
  }
}

// segment mean over CSR-contiguous concat rows -> agg[N][128] f32
__global__ __launch_bounds__(256) void agg_kernel(const int* __restrict__ offsets,
                                                  const unsigned short* __restrict__ concat,
                                                  float* __restrict__ agg) {
  int n = blockIdx.x * 4 + (threadIdx.x >> 6);
  if (n >= NN) return;
  int lane = threadIdx.x & 63;
  int s0 = offsets[n], s1 = offsets[n + 1];
  float a0 = 0.f, a1 = 0.f;
  const uint32_t* p = (const uint32_t*)concat + lane;
  for (int s = s0; s < s1; ++s) {
    uint32_t v = p[(size_t)s * 64];
    a0 += bf2f(v & 0xffffu);
    a1 += bf2f(v >> 16);
  }
  float inv = (s1 > s0) ? 1.f / (float)(s1 - s0) : 0.f;
  ((float2*)(agg + (size_t)n * 128))[lane] = make_float2(a0 * inv, a1 * inv);
}

// ---------------------------------------------------------------------------
// node_v3: barrier-free, one wave == 32 nodes. K = 448 (12 chunks + gs chunk).
// GatedMLP -> fused LayerNorm -> f32 out.
// ---------------------------------------------------------------------------
__global__ __launch_bounds__(256, 2) void node_v3(
    const float* __restrict__ node_inp, const float* __restrict__ coords,
    const float* __restrict__ gstate, const float* __restrict__ agg,
    const unsigned short* __restrict__ Wm0T, const unsigned short* __restrict__ Wg0T,
    const unsigned short* __restrict__ Wm1T, const unsigned short* __restrict__ Wg1T,
    const float* __restrict__ bm0, const float* __restrict__ bg0,
    const float* __restrict__ bm1, const float* __restrict__ bg1,
    const float* __restrict__ gamma, const float* __restrict__ beta,
    float* __restrict__ out) {
  __shared__ char smem[32768];
  const int t = threadIdx.x;
  const int lane = t & 63;
  const int wv = t >> 6;
  const int lg = lane >> 4;
  const int lr = lane & 15;
  char* hs = smem + wv * 8192;

  float b0m[8], b0g[8], b1m[8], b1g[8], gmr[8], btr[8];
#pragma unroll
  for (int nf = 0; nf < 8; ++nf) {
    b0m[nf] = bm0[nf * 16 + lr];
    b0g[nf] = bg0[nf * 16 + lr];
    b1m[nf] = bm1[nf * 16 + lr];
    b1g[nf] = bg1[nf * 16 + lr];
    gmr[nf] = gamma[nf * 16 + lr];
    btr[nf] = beta[nf * 16 + lr];
  }

  const int NT = (NN + 31) / 32;
  for (int tile = blockIdx.x * 4 + wv; tile < NT; tile += gridDim.x * 4) {
    const int tbase = tile * 32;
    const int rlo = min(tbase + lr, NN - 1);
    const int rhi = min(tbase + lr + 16, NN - 1);
    const float* blo[3] = {node_inp + (size_t)rlo * 128, agg + (size_t)rlo * 128,
                           coords + (size_t)rlo * 128};
    const float* bhi[3] = {node_inp + (size_t)rhi * 128, agg + (size_t)rhi * 128,
                           coords + (size_t)rhi * 128};

    f32x4 accm[2][8] = {};
    f32x4 accg[2][8] = {};

#pragma unroll
    for (int sel = 0; sel < 3; ++sel) {
      const float* plo = blo[sel] + lg * 8;
      const float* phi = bhi[sel] + lg * 8;
#pragma unroll 2
      for (int kq = 0; kq < 4; ++kq) {
        const int kc = sel * 4 + kq;
        float4 x0 = ((const float4*)(plo + kq * 32))[0];
        float4 x1 = ((const float4*)(plo + kq * 32))[1];
        float4 y0 = ((const float4*)(phi + kq * 32))[0];
        float4 y1 = ((const float4*)(phi + kq * 32))[1];
        bf16x8 alo = pack8(x0, x1);
        bf16x8 ahi = pack8(y0, y1);
        const int kof = kc * 32 + lg * 8;
#pragma unroll
        for (int nf = 0; nf < 8; ++nf) {
          const int wrow = (nf * 16 + lr) * 448 + kof;
          bf16x8 bm = ldb(Wm0T + wrow);
          accm[0][nf] = MFMA16(alo, bm, accm[0][nf]);
          accm[1][nf] = MFMA16(ahi, bm, accm[1][nf]);
          bf16x8 bg = ldb(Wg0T + wrow);
          accg[0][nf] = MFMA16(alo, bg, accg[0][nf]);
          accg[1][nf] = MFMA16(ahi, bg, accg[1][nf]);
        }
      }
    }
    // gs chunk: k=384 only (kc=12); k 385..447 are zero-padded in A and WT.
    {
      U8 z; z.q = make_uint4(0, 0, 0, 0);
      bf16x8 alo = z.v, ahi = z.v;
      if (lg == 0) {
        U8 a, b;
        a.q = make_uint4(f2bf(gstate[rlo]), 0, 0, 0);
        b.q = make_uint4(f2bf(gstate[rhi]), 0, 0, 0);
        alo = a.v; ahi = b.v;
      }
      const int kof = 384 + lg * 8;
#pragma unroll
      for (int nf = 0; nf < 8; ++nf) {
        const int wrow = (nf * 16 + lr) * 448 + kof;
        bf16x8 bm = ldb(Wm0T + wrow);
        accm[0][nf] = MFMA16(alo, bm, accm[0][nf]);
        accm[1][nf] = MFMA16(ahi, bm, accm[1][nf]);
        bf16x8 bg = ldb(Wg0T + wrow);
        accg[0][nf] = MFMA16(alo, bg, accg[0][nf]);
        accg[1][nf] = MFMA16(ahi, bg, accg[1][nf]);
      }
    }

    // ---- layer 2, branch m ----
    f32x4 acc2m[2][8] = {};
    f32x4 acc2g[2][8] = {};
#pragma unroll
    for (int mf = 0; mf < 2; ++mf)
#pragma unroll
      for (int nf = 0; nf < 8; ++nf)
#pragma unroll
        for (int r = 0; r < 4; ++r) {
          float h = accm[mf][nf][r] + b0m[nf];
          h = h * sigm(h);
          int row = mf * 16 + lg * 4 + r;
          *(unsigned short*)(hs + ((row * 256 + (nf * 16 + lr) * 2) ^ ((row & 7) << 4))) =
              (unsigned short)f2bf(h);
        }
#pragma unroll
    for (int kc = 0; kc < 4; ++kc) {
      const int kb = (kc * 32 + lg * 8) * 2;
      bf16x8 alo = *(const bf16x8*)(hs + ((lr * 256 + kb) ^ ((lr & 7) << 4)));
      bf16x8 ahi = *(const bf16x8*)(hs + (((lr + 16) * 256 + kb) ^ ((lr & 7) << 4)));
#pragma unroll
      for (int nf = 0; nf < 8; ++nf) {
        bf16x8 b = ldb(Wm1T + (nf * 16 + lr) * 128 + kc * 32 + lg * 8);
        acc2m[0][nf] = MFMA16(alo, b, acc2m[0][nf]);
        acc2m[1][nf] = MFMA16(ahi, b, acc2m[1][nf]);
      }
    }
    // ---- layer 2, branch g ----
#pragma unroll
    for (int mf = 0; mf < 2; ++mf)
#pragma unroll
      for (int nf = 0; nf < 8; ++nf)
#pragma unroll
        for (int r = 0; r < 4; ++r) {
          float h = accg[mf][nf][r] + b0g[nf];
          h = h * sigm(h);
          int row = mf * 16 + lg * 4 + r;
          *(unsigned short*)(hs + ((row * 256 + (nf * 16 + lr) * 2) ^ ((row & 7) << 4))) =
              (unsigned short)f2bf(h);
        }
#pragma unroll
    for (int kc = 0; kc < 4; ++kc) {
      const int kb = (kc * 32 + lg * 8) * 2;
      bf16x8 alo = *(const bf16x8*)(hs + ((lr * 256 + kb) ^ ((lr & 7) << 4)));
      bf16x8 ahi = *(const bf16x8*)(hs + (((lr + 16) * 256 + kb) ^ ((lr & 7) << 4)));
#pragma unroll
      for (int nf = 0; nf < 8; ++nf) {
        bf16x8 b = ldb(Wg1T + (nf * 16 + lr) * 128 + kc * 32 + lg * 8);
        acc2g[0][nf] = MFMA16(alo, b, acc2g[0][nf]);
        acc2g[1][nf] = MFMA16(ahi, b, acc2g[1][nf]);
      }
    }

    // ---- combine + LayerNorm + f32 store ----
#pragma unroll
    for (int mf = 0; mf < 2; ++mf)
#pragma unroll
      for (int r = 0; r < 4; ++r) {
        int rg = tbase + mf * 16 + lg * 4 + r;
        float v[8];
        float s = 0.f, ss = 0.f;
#pragma unroll
        for (int nf = 0; nf < 8; ++nf) {
          float mv = acc2m[mf][nf][r] + b1m[nf];
          float gv = sigm(acc2g[mf][nf][r] + b1g[nf]);
          v[nf] = mv * gv;
          s += v[nf];
          ss += v[nf] * v[nf];
        }
#pragma unroll
        for (int msk = 1; msk < 16; msk <<= 1) {
          s += __shfl_xor(s, msk, 64);
          ss += __shfl_xor(ss, msk, 64);
        }
        float mu = s * 0.0078125f;
        float var = ss * 0.0078125f - mu * mu;
        float rs = rsqrtf(var + 1e-5f);
        if (rg < NN) {
#pragma unroll
          for (int nf = 0; nf < 8; ++nf)
            out[(size_t)rg * 128 + nf * 16 + lr] = (v[nf] - mu) * rs * gmr[nf] + btr[nf];
        }
      }
  }
}

// ---------------------------------------------------------------------------
// Fallback (ws too small): old barriered atomic-scatter bond + div.
// ---------------------------------------------------------------------------
__global__ __launch_bounds__(256) void bond_fallback(
    const float* __restrict__ node_inp, const float* __restrict__ edge_feat,
    const int* __restrict__ ei,
    const unsigned short* __restrict__ Wm0T, const unsigned short* __restrict__ Wg0T,
    const unsigned short* __restrict__ Wm1T, const unsigned short* __restrict__ Wg1T,
    const float* __restrict__ bm0, const float* __restrict__ bg0,
    const float* __restrict__ bm1, const float* __restrict__ bg1,
    float* __restrict__ agg) {
  __shared__ char smem[32768];
  const int t = threadIdx.x;
  const int lane = t & 63;
  const int wv = t >> 6;
  const int lg = lane >> 4;
  const int lr = lane & 15;
  char* hs = smem + wv * 8192;

  float b0m[8], b0g[8], b1m[8], b1g[8];
#pragma unroll
  for (int nf = 0; nf < 8; ++nf) {
    b0m[nf] = bm0[nf * 16 + lr];
    b0g[nf] = bg0[nf * 16 + lr];
    b1m[nf] = bm1[nf * 16 + lr];
    b1g[nf] = bg1[nf * 16 + lr];
  }

  const int NT = NE / 32;
  for (int tile = blockIdx.x * 4 + wv; tile < NT; tile += gridDim.x * 4) {
    const int tbase = tile * 32;
    const int rlo = tbase + lr, rhi = rlo + 16;
    const float* blo[3] = {node_inp + (size_t)ei[rlo] * 128,
                           node_inp + (size_t)ei[NE + rlo] * 128,
                           edge_feat + (size_t)rlo * 128};
    const float* bhi[3] = {node_inp + (size_t)ei[rhi] * 128,
                           node_inp + (size_t)ei[NE + rhi] * 128,
                           edge_feat + (size_t)rhi * 128};

    f32x4 accm[2][8] = {};
    f32x4 accg[2][8] = {};
#pragma unroll
    for (int sel = 0; sel < 3; ++sel) {
      const float* plo = blo[sel] + lg * 8;
      const float* phi = bhi[sel] + lg * 8;
#pragma unroll 2
      for (int kq = 0; kq < 4; ++kq) {
        const int kc = sel * 4 + kq;
        bf16x8 alo = pack8(((const float4*)(plo + kq * 32))[0],
                           ((const float4*)(plo + kq * 32))[1]);
        bf16x8 ahi = pack8(((const float4*)(phi + kq * 32))[0],
                           ((const float4*)(phi + kq * 32))[1]);
        const int kof = kc * 32 + lg * 8;
#pragma unroll
        for (int nf = 0; nf < 8; ++nf) {
          const int wrow = (nf * 16 + lr) * 384 + kof;
          bf16x8 bm = ldb(Wm0T + wrow);
          accm[0][nf] = MFMA16(alo, bm, accm[0][nf]);
          accm[1][nf] = MFMA16(ahi, bm, accm[1][nf]);
          bf16x8 bg = ldb(Wg0T + wrow);
          accg[0][nf] = MFMA16(alo, bg, accg[0][nf]);
          accg[1][nf] = MFMA16(ahi, bg, accg[1][nf]);
        }
      }
    }
    f32x4 acc2m[2][8] = {};
    f32x4 acc2g[2][8] = {};
#pragma unroll
    for (int mf = 0; mf < 2; ++mf)
#pragma unroll
      for (int nf = 0; nf < 8; ++nf)
#pragma unroll
        for (int r = 0; r < 4; ++r) {
          float h = accm[mf][nf][r] + b0m[nf];
          h = h * sigm(h);
          int row = mf * 16 + lg * 4 + r;
          *(unsigned short*)(hs + ((row * 256 + (nf * 16 + lr) * 2) ^ ((row & 7) << 4))) =
              (unsigned short)f2bf(h);
        }
#pragma unroll
    for (int kc = 0; kc < 4; ++kc) {
      const int kb = (kc * 32 + lg * 8) * 2;
      bf16x8 alo = *(const bf16x8*)(hs + ((lr * 256 + kb) ^ ((lr & 7) << 4)));
      bf16x8 ahi = *(const bf16x8*)(hs + (((lr + 16) * 256 + kb) ^ ((lr & 7) << 4)));
#pragma unroll
      for (int nf = 0; nf < 8; ++nf) {
        bf16x8 b = ldb(Wm1T + (nf * 16 + lr) * 128 + kc * 32 + lg * 8);
        acc2m[0][nf] = MFMA16(alo, b, acc2m[0][nf]);
        acc2m[1][nf] = MFMA16(ahi, b, acc2m[1][nf]);
      }
    }
#pragma unroll
    for (int mf = 0; mf < 2; ++mf)
#pragma unroll
      for (int nf = 0; nf < 8; ++nf)
#pragma unroll
        for (int r = 0; r < 4; ++r) {
          float h = accg[mf][nf][r] + b0g[nf];
          h = h * sigm(h);
          int row = mf * 16 + lg * 4 + r;
          *(unsigned short*)(hs + ((row * 256 + (nf * 16 + lr) * 2) ^ ((row & 7) << 4))) =
              (unsigned short)f2bf(h);
        }
#pragma unroll
    for (int kc = 0; kc < 4; ++kc) {
      const int kb = (kc * 32 + lg * 8) * 2;
      bf16x8 alo = *(const bf16x8*)(hs + ((lr * 256 + kb) ^ ((lr & 7) << 4)));
      bf16x8 ahi = *(const bf16x8*)(hs + (((lr + 16) * 256 + kb) ^ ((lr & 7) << 4)));
#pragma unroll
      for (int nf = 0; nf < 8; ++nf) {
        bf16x8 b = ldb(Wg1T + (nf * 16 + lr) * 128 + kc * 32 + lg * 8);
        acc2g[0][nf] = MFMA16(alo, b, acc2g[0][nf]);
        acc2g[1][nf] = MFMA16(ahi, b, acc2g[1][nf]);
      }
    }
#pragma unroll
    for (int mf = 0; mf < 2; ++mf)
#pragma unroll
      for (int r = 0; r < 4; ++r) {
        int row = mf * 16 + lg * 4 + r;
        int s = ei[tbase + row];
        float* dp = agg + (size_t)s * 128;
#pragma unroll
        for (int nf = 0; nf < 8; ++nf) {
          float mv = acc2m[mf][nf][r] + b1m[nf];
          float gv = sigm(acc2g[mf][nf][r] + b1g[nf]);
          atomicAdd(dp + nf * 16 + lr, mv * gv);
        }
      }
  }
}

__global__ __launch_bounds__(256) void div_kernel(float* __restrict__ agg,
                                                  const int* __restrict__ cnt) {
  int id = blockIdx.x * 256 + threadIdx.x;
  if (id >= NN * 128) return;
  int c = cnt[id >> 7];
  agg[id] = c > 0 ? agg[id] / (float)c : 0.f;
}

extern "C" void kernel_launch(void* const* d_in, const int* in_sizes, int n_in,
                              void* d_out, int out_size, void* d_ws, size_t ws_size,
                              hipStream_t stream) {
  const float* node_inp = (const float*)d_in[0];
  const float* edge_feat = (const float*)d_in[1];
  const float* gstate = (const float*)d_in[2];
  const float* coords = (const float*)d_in[4];
  const int* edge_index = (const int*)d_in[5];
  const float* bWm0 = (const float*)d_in[6];  const float* bbm0 = (const float*)d_in[7];
  const float* bWm1 = (const float*)d_in[8];  const float* bbm1 = (const float*)d_in[9];
  const float* bWg0 = (const float*)d_in[10]; const float* bbg0 = (const float*)d_in[11];
  const float* bWg1 = (const float*)d_in[12]; const float* bbg1 = (const float*)d_in[13];
  const float* nWm0 = (const float*)d_in[14]; const float* nbm0 = (const float*)d_in[15];
  const float* nWm1 = (const float*)d_in[16]; const float* nbm1 = (const float*)d_in[17];
  const float* nWg0 = (const float*)d_in[18]; const float* nbg0 = (const float*)d_in[19];
  const float* nWg1 = (const float*)d_in[20]; const float* nbg1 = (const float*)d_in[21];
  const float* gamma = (const float*)d_in[22]; const float* beta = (const float*)d_in[23];

  char* ws = (char*)d_ws;
  size_t o = 0;
  auto alloc = [&](size_t bytes) {
    size_t r = o; o = (o + bytes + 255) & ~(size_t)255; return r;
  };
  float* agg        = (float*)(ws + alloc((size_t)NN * 128 * 4));
  int* cnt          = (int*)(ws + alloc((size_t)NN * 4));
  size_t cnt_end = o;
  int* offsets      = (int*)(ws + alloc((size_t)(NN + 1) * 4));
  int* cursor       = (int*)(ws + alloc((size_t)NN * 4));
  int* partials     = (int*)(ws + alloc(1024));
  unsigned short* bWm0T = (unsigned short*)(ws + alloc(128 * 384 * 2));
  unsigned short* bWg0T = (unsigned short*)(ws + alloc(128 * 384 * 2));
  unsigned short* bWm1T = (unsigned short*)(ws + alloc(128 * 128 * 2));
  unsigned short* bWg1T = (unsigned short*)(ws + alloc(128 * 128 * 2));
  unsigned short* nWm0T = (unsigned short*)(ws + alloc(128 * 448 * 2));
  unsigned short* nWg0T = (unsigned short*)(ws + alloc(128 * 448 * 2));
  unsigned short* nWm1T = (unsigned short*)(ws + alloc(128 * 128 * 2));
  unsigned short* nWg1T = (unsigned short*)(ws + alloc(128 * 128 * 2));
  size_t fallback_need = o;
  int* eidS         = (int*)(ws + alloc((size_t)NE * 4));
  int* srcS         = (int*)(ws + alloc((size_t)NE * 4));
  int* dstS         = (int*)(ws + alloc((size_t)NE * 4));
  unsigned short* concat = (unsigned short*)(ws + alloc((size_t)NE * 128 * 2));
  size_t csr_need = o;

  const bool csr = ws_size >= csr_need;

  // zero cnt (and agg in fallback mode — atomics accumulate into it)
  if (csr) hipMemsetAsync(cnt, 0, (size_t)NN * 4, stream);
  else     hipMemsetAsync(ws, 0, cnt_end, stream);

  auto packl = [&](const float* W, unsigned short* WT, int K, int Kpad) {
    int total = 128 * Kpad;
    pack_wT<<<(total + 255) / 256, 256, 0, stream>>>(W, WT, K, Kpad);
  };
  packl(bWm0, bWm0T, 384, 384);
  packl(bWg0, bWg0T, 384, 384);
  packl(bWm1, bWm1T, 128, 128);
  packl(bWg1, bWg1T, 128, 128);
  packl(nWm0, nWm0T, 385, 448);
  packl(nWg0, nWg0T, 385, 448);
  packl(nWm1, nWm1T, 128, 128);
  packl(nWg1, nWg1T, 128, 128);

  if (csr) {
    hist_kernel<<<NE / 256, 256, 0, stream>>>(edge_index, cnt);
    scan1<<<NPART, 256, 0, stream>>>(cnt, partials);
    scan2<<<1, 256, 0, stream>>>(partials, offsets);
    scan3<<<NPART, 256, 0, stream>>>(cnt, partials, offsets, cursor);
    fill_kernel<<<NE / 256, 256, 0, stream>>>(edge_index, cursor, eidS, srcS, dstS);
    bond_v3<<<1024, 256, 0, stream>>>(
        node_inp, edge_feat, srcS, dstS, eidS,
        bWm0T, bWg0T, bWm1T, bWg1T, bbm0, bbg0, bbm1, bbg1, concat);
    agg_kernel<<<(NN + 3) / 4, 256, 0, stream>>>(offsets, concat, agg);
  } else {
    hist_kernel<<<NE / 256, 256, 0, stream>>>(edge_index, cnt);
    bond_fallback<<<1024, 256, 0, stream>>>(
        node_inp, edge_feat, edge_index,
        bWm0T, bWg0T, bWm1T, bWg1T, bbm0, bbg0, bbm1, bbg1, agg);
    div_kernel<<<(NN * 128 + 255) / 256, 256, 0, stream>>>(agg, cnt);
  }

  node_v3<<<392, 256, 0, stream>>>(
      node_inp, coords, gstate, agg, nWm0T, nWg0T, nWm1T, nWg1T,
      nbm0, nbg0, nbm1, nbg1, gamma, beta, (float*)d_out);
}

// Round 4
// 1104.103 us; speedup vs baseline: 2.2468x; 2.2468x over previous
//
#include <hip/hip_runtime.h>
#include <stdint.h>

// GeneralConv fused pipeline for MI355X (gfx950) — v4.
// Factorized bond layer1: x@W0 = PS[src] + QS[dst] + edge_feat@W0e, so the
// in-loop weights (W0e + W1, both branches) fit in 128 KB LDS, staged ONCE per
// block (single barrier), then a barrier-free grid-stride tile loop.
// PS table lives in d_out (dead before node kernel writes). concat in CSR slot
// order -> streaming segment mean -> node kernel (Znode precompute + agg@W
// K=128 + layer2 + fused LayerNorm).

#define NN 50000
#define NE 800000
#define NPART 196        // ceil(NN/256)
#define NTILE_E 25000    // NE/32
#define NTILE_N 1563     // ceil(NN/32)

typedef short bf16x8 __attribute__((ext_vector_type(8)));
typedef float f32x4 __attribute__((ext_vector_type(4)));

#define MFMA16(a, b, c) __builtin_amdgcn_mfma_f32_16x16x32_bf16((a), (b), (c), 0, 0, 0)

union U8 { uint4 q; bf16x8 v; };

__device__ __forceinline__ uint32_t f2bf(float f) {
  union { float f; uint32_t u; } x; x.f = f;
  uint32_t u = x.u;
  u += 0x7FFFu + ((u >> 16) & 1u);   // RNE
  return u >> 16;
}
__device__ __forceinline__ float bf2f(uint32_t lo16) {
  union { uint32_t u; float f; } x; x.u = lo16 << 16; return x.f;
}
__device__ __forceinline__ float sigm(float x) { return 1.0f / (1.0f + __expf(-x)); }
__device__ __forceinline__ float silu(float x) { return x * sigm(x); }
__device__ __forceinline__ uint32_t packbf2(float a, float b) {
  return f2bf(a) | (f2bf(b) << 16);
}
__device__ __forceinline__ bf16x8 pack8(float4 a, float4 b) {
  U8 u;
  u.q.x = packbf2(a.x, a.y); u.q.y = packbf2(a.z, a.w);
  u.q.z = packbf2(b.x, b.y); u.q.w = packbf2(b.z, b.w);
  return u.v;
}
__device__ __forceinline__ f32x4 cvt4(const unsigned short* p) {
  uint2 a = *(const uint2*)p;
  f32x4 r;
  r[0] = bf2f(a.x & 0xffffu); r[1] = bf2f(a.x >> 16);
  r[2] = bf2f(a.y & 0xffffu); r[3] = bf2f(a.y >> 16);
  return r;
}
__device__ __forceinline__ f32x4 pq4(const unsigned short* p, const unsigned short* q) {
  f32x4 a = cvt4(p), b = cvt4(q);
  f32x4 r; r[0] = a[0] + b[0]; r[1] = a[1] + b[1]; r[2] = a[2] + b[2]; r[3] = a[3] + b[3];
  return r;
}
// swizzled LDS weight-fragment read: region layout [rows][128 k] bf16, 256B rows
__device__ __forceinline__ bf16x8 ldw(const char* base, int row, int kc, int lg) {
  return *(const bf16x8*)(base + ((row * 256 + kc * 64 + lg * 16) ^ ((row & 7) << 4)));
}
__device__ __forceinline__ void stage_w(char* dst, const unsigned short* src, int tid) {
  for (int g = tid; g < 4096; g += 512) {
    int row = g >> 4, slot = g & 15;
    *(uint4*)(dst + ((row * 256 + slot * 16) ^ ((row & 7) << 4))) =
        *(const uint4*)(src + row * 128 + slot * 8);
  }
}

// pack: WT[(c0+c)*Kpad + k] = bf16(W[(srcRowBase+k)*128 + c]) for c in [0,128)
__global__ void pack_seg(const float* __restrict__ W, int srcRowBase, int nK,
                         unsigned short* __restrict__ WT, int c0, int Kpad) {
  int id = blockIdx.x * 256 + threadIdx.x;
  if (id >= 128 * Kpad) return;
  int c = id / Kpad, k = id - c * Kpad;
  WT[(size_t)(c0 + c) * Kpad + k] =
      (unsigned short)f2bf(k < nK ? W[(size_t)(srcRowBase + k) * 128 + c] : 0.0f);
}

// zn weights: [256 c][288 k]; k<128 -> W rows k (node_inp), 128..255 -> rows 256+k-128
// (coords), k==256 -> row 384 (gs), else 0. c<128: Wm, else Wg.
__global__ void znpack(const float* __restrict__ Wm, const float* __restrict__ Wg,
                       unsigned short* __restrict__ WT) {
  int id = blockIdx.x * 256 + threadIdx.x;
  if (id >= 256 * 288) return;
  int c = id / 288, k = id - c * 288;
  const float* W = (c < 128) ? Wm : Wg;
  int cc = c & 127;
  float v = 0.0f;
  if (k < 128) v = W[(size_t)k * 128 + cc];
  else if (k < 256) v = W[(size_t)(128 + k) * 128 + cc];   // 256 + (k-128)
  else if (k == 256) v = W[(size_t)384 * 128 + cc];
  WT[id] = (unsigned short)f2bf(v);
}

// ---------------- CSR build ----------------
__global__ __launch_bounds__(256) void hist_kernel(const int* __restrict__ ei,
                                                   int* __restrict__ cnt) {
  int e = blockIdx.x * 256 + threadIdx.x;
  if (e < NE) atomicAdd(&cnt[ei[e]], 1);
}

__global__ __launch_bounds__(256) void scan1(const int* __restrict__ cnt,
                                             int* __restrict__ partials) {
  int t = threadIdx.x;
  int i = blockIdx.x * 256 + t;
  int v = (i < NN) ? cnt[i] : 0;
#pragma unroll
  for (int d = 1; d < 64; d <<= 1) v += __shfl_xor(v, d, 64);
  __shared__ int ws4[4];
  if ((t & 63) == 0) ws4[t >> 6] = v;
  __syncthreads();
  if (t == 0) partials[blockIdx.x] = ws4[0] + ws4[1] + ws4[2] + ws4[3];
}

__global__ __launch_bounds__(256) void scan2(int* __restrict__ partials,
                                             int* __restrict__ offsets) {
  int t = threadIdx.x;
  int v = (t < NPART) ? partials[t] : 0;
  int incl = v;
#pragma unroll
  for (int d = 1; d < 64; d <<= 1) {
    int u = __shfl_up(incl, d, 64);
    if ((t & 63) >= d) incl += u;
  }
  __shared__ int wsum[4];
  if ((t & 63) == 63) wsum[t >> 6] = incl;
  __syncthreads();
  int add = 0;
  for (int w = 0; w < (t >> 6); ++w) add += wsum[w];
  incl += add;
  if (t < NPART) partials[t] = incl - v;
  if (t == 255) offsets[NN] = incl;
}

__global__ __launch_bounds__(256) void scan3(const int* __restrict__ cnt,
                                             const int* __restrict__ partials,
                                             int* __restrict__ offsets,
                                             int* __restrict__ cursor) {
  int t = threadIdx.x;
  int i = blockIdx.x * 256 + t;
  int v = (i < NN) ? cnt[i] : 0;
  int incl = v;
#pragma unroll
  for (int d = 1; d < 64; d <<= 1) {
    int u = __shfl_up(incl, d, 64);
    if ((t & 63) >= d) incl += u;
  }
  __shared__ int wsum[4];
  if ((t & 63) == 63) wsum[t >> 6] = incl;
  __syncthreads();
  int add = partials[blockIdx.x];
  for (int w = 0; w < (t >> 6); ++w) add += wsum[w];
  int excl = incl - v + add;
  if (i < NN) { offsets[i] = excl; cursor[i] = excl; }
}

__global__ __launch_bounds__(256) void fill_kernel(const int* __restrict__ ei,
                                                   int* __restrict__ cursor,
                                                   int* __restrict__ slotOf) {
  int e = blockIdx.x * 256 + threadIdx.x;
  if (e >= NE) return;
  slotOf[e] = atomicAdd(&cursor[ei[e]], 1);
}

// ---------------------------------------------------------------------------
// pq_kernel: PS[n][256] = [node_inp@Wm0[0:128]+bm0 | node_inp@Wg0[0:128]+bg0]
//            QS[n][256] = [node_inp@Wm0[128:256]   | node_inp@Wg0[128:256]]
// bf16 tables. One wave = 32 nodes. Weights (2x64KB) staged in LDS once.
// ---------------------------------------------------------------------------
template <bool BIAS>
__device__ __forceinline__ void pq_table(const char* wbase, const bf16x8 (&xf)[2][4],
                                         const float* bm, const float* bg,
                                         unsigned short* out, int tb, int lg, int lr) {
  f32x4 acc[2][16] = {};
#pragma unroll
  for (int kc = 0; kc < 4; ++kc)
#pragma unroll
    for (int cf = 0; cf < 16; ++cf) {
      bf16x8 a = ldw(wbase, cf * 16 + lr, kc, lg);
      acc[0][cf] = MFMA16(a, xf[0][kc], acc[0][cf]);
      acc[1][cf] = MFMA16(a, xf[1][kc], acc[1][cf]);
    }
#pragma unroll
  for (int cf = 0; cf < 16; ++cf) {
    int c = cf * 16 + lg * 4;
    float4 b = make_float4(0.f, 0.f, 0.f, 0.f);
    if (BIAS) b = *(const float4*)((cf < 8) ? (bm + c) : (bg + (c - 128)));
#pragma unroll
    for (int et = 0; et < 2; ++et) {
      int n = tb + et * 16 + lr;
      if (n < NN) {
        f32x4 v = acc[et][cf];
        uint2 pk = make_uint2(packbf2(v[0] + b.x, v[1] + b.y),
                              packbf2(v[2] + b.z, v[3] + b.w));
        *(uint2*)(out + (size_t)n * 256 + c) = pk;
      }
    }
  }
}

__global__ __launch_bounds__(512, 2) void pq_kernel(
    const float* __restrict__ ni,
    const unsigned short* __restrict__ pW, const unsigned short* __restrict__ qW,
    const float* __restrict__ bbm0, const float* __restrict__ bbg0,
    unsigned short* __restrict__ PS, unsigned short* __restrict__ QS) {
  __shared__ char sm[131072];
  const int t = threadIdx.x, lane = t & 63, wv = t >> 6, lg = lane >> 4, lr = lane & 15;
  stage_w(sm, pW, t);
  stage_w(sm + 65536, qW, t);
  __syncthreads();
  int tile = blockIdx.x * 8 + wv;
  if (tile >= NTILE_N) return;
  int tb = tile * 32;
  int n0 = min(tb + lr, NN - 1), n1 = min(tb + 16 + lr, NN - 1);
  bf16x8 xf[2][4];
#pragma unroll
  for (int kc = 0; kc < 4; ++kc) {
    const float* p0 = ni + (size_t)n0 * 128 + kc * 32 + lg * 8;
    const float* p1 = ni + (size_t)n1 * 128 + kc * 32 + lg * 8;
    xf[0][kc] = pack8(((const float4*)p0)[0], ((const float4*)p0)[1]);
    xf[1][kc] = pack8(((const float4*)p1)[0], ((const float4*)p1)[1]);
  }
  pq_table<true>(sm, xf, bbm0, bbg0, PS, tb, lg, lr);
  pq_table<false>(sm + 65536, xf, nullptr, nullptr, QS, tb, lg, lr);
}

// ---------------------------------------------------------------------------
// zn_kernel: Znode[n][256] bf16 = [zm | zg], z = node_inp@W[0:128] +
// coords@W[256:384] + gs*W[384] + b0. Weights [256][288] bf16 = 144KB LDS.
// ---------------------------------------------------------------------------
__global__ __launch_bounds__(512, 2) void zn_kernel(
    const float* __restrict__ ni, const float* __restrict__ coords,
    const float* __restrict__ gs, const unsigned short* __restrict__ znW,
    const float* __restrict__ nbm0, const float* __restrict__ nbg0,
    unsigned short* __restrict__ ZN) {
  __shared__ char sm[147456];
  const int t = threadIdx.x, lane = t & 63, wv = t >> 6, lg = lane >> 4, lr = lane & 15;
  for (int g = t; g < 9216; g += 512) {
    int row = g >> 5, slot = g & 31;   // wait: 288k*2B = 576B rows -> 36 slots, not 32
  }
  // re-stage correctly: 256 rows x 36 slots of 16B
  for (int g = t; g < 256 * 36; g += 512) {
    int row = g / 36, slot = g - row * 36;
    *(uint4*)(sm + ((row * 576 + slot * 16) ^ ((row & 7) << 4))) =
        *(const uint4*)(znW + row * 288 + slot * 8);
  }
  __syncthreads();
  int tile = blockIdx.x * 8 + wv;
  if (tile >= NTILE_N) return;
  int tb = tile * 32;
  int n0 = min(tb + lr, NN - 1), n1 = min(tb + 16 + lr, NN - 1);
  bf16x8 xf[2][9];
#pragma unroll
  for (int kc = 0; kc < 4; ++kc) {
    const float* p0 = ni + (size_t)n0 * 128 + kc * 32 + lg * 8;
    const float* p1 = ni + (size_t)n1 * 128 + kc * 32 + lg * 8;
    xf[0][kc] = pack8(((const float4*)p0)[0], ((const float4*)p0)[1]);
    xf[1][kc] = pack8(((const float4*)p1)[0], ((const float4*)p1)[1]);
    const float* q0 = coords + (size_t)n0 * 128 + kc * 32 + lg * 8;
    const float* q1 = coords + (size_t)n1 * 128 + kc * 32 + lg * 8;
    xf[0][4 + kc] = pack8(((const float4*)q0)[0], ((const float4*)q0)[1]);
    xf[1][4 + kc] = pack8(((const float4*)q1)[0], ((const float4*)q1)[1]);
  }
  {
    U8 z0, z1;
    z0.q = make_uint4(0, 0, 0, 0); z1.q = make_uint4(0, 0, 0, 0);
    if (lg == 0) { z0.q.x = f2bf(gs[n0]); z1.q.x = f2bf(gs[n1]); }
    xf[0][8] = z0.v; xf[1][8] = z1.v;
  }
  f32x4 acc[2][16] = {};
#pragma unroll
  for (int kc = 0; kc < 9; ++kc)
#pragma unroll
    for (int cf = 0; cf < 16; ++cf) {
      int row = cf * 16 + lr;
      bf16x8 a = *(const bf16x8*)(sm + ((row * 576 + kc * 64 + lg * 16) ^ ((row & 7) << 4)));
      acc[0][cf] = MFMA16(a, xf[0][kc], acc[0][cf]);
      acc[1][cf] = MFMA16(a, xf[1][kc], acc[1][cf]);
    }
#pragma unroll
  for (int cf = 0; cf < 16; ++cf) {
    int c = cf * 16 + lg * 4;
    float4 b = *(const float4*)((cf < 8) ? (nbm0 + c) : (nbg0 + (c - 128)));
#pragma unroll
    for (int et = 0; et < 2; ++et) {
      int n = tb + et * 16 + lr;
      if (n < NN) {
        f32x4 v = acc[et][cf];
        uint2 pk = make_uint2(packbf2(v[0] + b.x, v[1] + b.y),
                              packbf2(v[2] + b.z, v[3] + b.w));
        *(uint2*)(ZN + (size_t)n * 256 + c) = pk;
      }
    }
  }
}

// ---------------------------------------------------------------------------
// shared layer2 helper: silu(acc) -> per-wave LDS quarter-buffer [32][40B-pad]
// -> B-frags -> MFMA with LDS-staged W1 rows [rowoff..rowoff+128).
// ---------------------------------------------------------------------------
__device__ __forceinline__ void layer2(const f32x4 (&acc)[2][8], f32x4 (&acc2)[2][8],
                                       const char* w1, int rowoff, char* scr,
                                       int lg, int lr) {
#pragma unroll
  for (int q = 0; q < 4; ++q) {
#pragma unroll
    for (int hq = 0; hq < 2; ++hq) {
      int hf = q * 2 + hq;
#pragma unroll
      for (int et = 0; et < 2; ++et) {
        f32x4 z = acc[et][hf];
        uint2 pk = make_uint2(packbf2(silu(z[0]), silu(z[1])),
                              packbf2(silu(z[2]), silu(z[3])));
        *(uint2*)(scr + (et * 16 + lr) * 80 + hq * 32 + lg * 8) = pk;
      }
    }
#pragma unroll
    for (int et = 0; et < 2; ++et) {
      bf16x8 h = *(const bf16x8*)(scr + (et * 16 + lr) * 80 + lg * 16);
#pragma unroll
      for (int hf2 = 0; hf2 < 8; ++hf2) {
        bf16x8 a = ldw(w1, rowoff + hf2 * 16 + lr, q, lg);
        acc2[et][hf2] = MFMA16(a, h, acc2[et][hf2]);
      }
    }
  }
}

// ---------------------------------------------------------------------------
// bond_v4: weights in LDS (one barrier), barrier-free tile loop. One wave =
// 32 edges (original order). acc init = PS[src]+QS[dst] fragment gathers;
// layer1 adds edge_feat@W0e; layer2 per branch; out -> concat[slotOf[e]].
// ---------------------------------------------------------------------------
__global__ __launch_bounds__(512, 2) void bond_v4(
    const float* __restrict__ ef, const int* __restrict__ ei,
    const int* __restrict__ slotOf,
    const unsigned short* __restrict__ W0eT, const unsigned short* __restrict__ W1T,
    const unsigned short* __restrict__ PS, const unsigned short* __restrict__ QS,
    const float* __restrict__ bbm1, const float* __restrict__ bbg1,
    unsigned short* __restrict__ concat) {
  __shared__ char sm[152576];   // W0e 64K | W1 64K | consts 1K | scratch 8*2560
  const int t = threadIdx.x, lane = t & 63, wv = t >> 6, lg = lane >> 4, lr = lane & 15;
  stage_w(sm, W0eT, t);          // rows 0..127 m, 128..255 g (K=128)
  stage_w(sm + 65536, W1T, t);   // rows 0..127 W1m, 128..255 W1g
  if (t < 128) {
    ((float*)(sm + 131072))[t] = bbm1[t];
    ((float*)(sm + 131584))[t] = bbg1[t];
  }
  __syncthreads();
  char* scr = sm + 132096 + wv * 2560;

  const int wid = blockIdx.x * 8 + wv;         // 2048 waves
  const int start = wid * 13;
  const int end = min(start + 13, NTILE_E);
  for (int tile = start; tile < end; ++tile) {
    const int tb = tile * 32;
    const int e0 = tb + lr, e1 = tb + 16 + lr;
    const int s0 = ei[e0], s1 = ei[e1];
    const int d0 = ei[NE + e0], d1 = ei[NE + e1];

    f32x4 accm[2][8], accg[2][8];
#pragma unroll
    for (int hf = 0; hf < 8; ++hf) {
      const int hb = hf * 16 + lg * 4;
      accm[0][hf] = pq4(PS + (size_t)s0 * 256 + hb, QS + (size_t)d0 * 256 + hb);
      accm[1][hf] = pq4(PS + (size_t)s1 * 256 + hb, QS + (size_t)d1 * 256 + hb);
      accg[0][hf] = pq4(PS + (size_t)s0 * 256 + 128 + hb, QS + (size_t)d0 * 256 + 128 + hb);
      accg[1][hf] = pq4(PS + (size_t)s1 * 256 + 128 + hb, QS + (size_t)d1 * 256 + 128 + hb);
    }
#pragma unroll
    for (int kc = 0; kc < 4; ++kc) {
      const float* q0 = ef + (size_t)e0 * 128 + kc * 32 + lg * 8;
      const float* q1 = ef + (size_t)e1 * 128 + kc * 32 + lg * 8;
      bf16x8 x0 = pack8(((const float4*)q0)[0], ((const float4*)q0)[1]);
      bf16x8 x1 = pack8(((const float4*)q1)[0], ((const float4*)q1)[1]);
#pragma unroll
      for (int hf = 0; hf < 8; ++hf) {
        bf16x8 am = ldw(sm, hf * 16 + lr, kc, lg);
        bf16x8 ag = ldw(sm, 128 + hf * 16 + lr, kc, lg);
        accm[0][hf] = MFMA16(am, x0, accm[0][hf]);
        accm[1][hf] = MFMA16(am, x1, accm[1][hf]);
        accg[0][hf] = MFMA16(ag, x0, accg[0][hf]);
        accg[1][hf] = MFMA16(ag, x1, accg[1][hf]);
      }
    }

    f32x4 acc2m[2][8] = {};
    layer2(accm, acc2m, sm + 65536, 0, scr, lg, lr);
    f32x4 acc2g[2][8] = {};
    layer2(accg, acc2g, sm + 65536, 128, scr, lg, lr);

    const int sl0 = slotOf[e0], sl1 = slotOf[e1];
#pragma unroll
    for (int hf2 = 0; hf2 < 8; ++hf2) {
      float4 b1m = *(const float4*)(sm + 131072 + (hf2 * 16 + lg * 4) * 4);
      float4 b1g = *(const float4*)(sm + 131584 + (hf2 * 16 + lg * 4) * 4);
#pragma unroll
      for (int et = 0; et < 2; ++et) {
        f32x4 m = acc2m[et][hf2], g = acc2g[et][hf2];
        float o0 = (m[0] + b1m.x) * sigm(g[0] + b1g.x);
        float o1 = (m[1] + b1m.y) * sigm(g[1] + b1g.y);
        float o2 = (m[2] + b1m.z) * sigm(g[2] + b1g.z);
        float o3 = (m[3] + b1m.w) * sigm(g[3] + b1g.w);
        uint2 pk = make_uint2(packbf2(o0, o1), packbf2(o2, o3));
        int sl = et ? sl1 : sl0;
        *(uint2*)(concat + (size_t)sl * 128 + hf2 * 16 + lg * 4) = pk;
      }
    }
  }
}

// segment mean over CSR-contiguous concat rows -> agg[N][128] bf16
__global__ __launch_bounds__(256) void agg_kernel(const int* __restrict__ offsets,
                                                  const unsigned short* __restrict__ concat,
                                                  unsigned short* __restrict__ agg) {
  int n = blockIdx.x * 4 + (threadIdx.x >> 6);
  if (n >= NN) return;
  int lane = threadIdx.x & 63;
  int s0 = offsets[n], s1 = offsets[n + 1];
  float a0 = 0.f, a1 = 0.f;
  const uint32_t* p = (const uint32_t*)concat + lane;
  for (int s = s0; s < s1; ++s) {
    uint32_t v = p[(size_t)s * 64];
    a0 += bf2f(v & 0xffffu);
    a1 += bf2f(v >> 16);
  }
  float inv = (s1 > s0) ? 1.f / (float)(s1 - s0) : 0.f;
  ((uint32_t*)agg)[(size_t)n * 64 + lane] = packbf2(a0 * inv, a1 * inv);
}

// ---------------------------------------------------------------------------
// node_v4: acc init from Znode, + agg@Wagg (K=128), layer2, fused LayerNorm.
// ---------------------------------------------------------------------------
__global__ __launch_bounds__(512, 2) void node_v4(
    const unsigned short* __restrict__ agg, const unsigned short* __restrict__ ZN,
    const unsigned short* __restrict__ WaggT, const unsigned short* __restrict__ W1T,
    const float* __restrict__ nbm1, const float* __restrict__ nbg1,
    const float* __restrict__ gamma, const float* __restrict__ beta,
    float* __restrict__ out) {
  __shared__ char sm[153600];   // Wagg 64K | W1 64K | consts 2K | scratch 8*2560
  const int t = threadIdx.x, lane = t & 63, wv = t >> 6, lg = lane >> 4, lr = lane & 15;
  stage_w(sm, WaggT, t);
  stage_w(sm + 65536, W1T, t);
  if (t < 128) {
    ((float*)(sm + 131072))[t] = nbm1[t];
    ((float*)(sm + 131584))[t] = nbg1[t];
    ((float*)(sm + 132096))[t] = gamma[t];
    ((float*)(sm + 132608))[t] = beta[t];
  }
  __syncthreads();
  char* scr = sm + 133120 + wv * 2560;

  int tile = blockIdx.x * 8 + wv;
  if (tile >= NTILE_N) return;
  int tb = tile * 32;
  int n0 = min(tb + lr, NN - 1), n1 = min(tb + 16 + lr, NN - 1);

  f32x4 accm[2][8], accg[2][8];
#pragma unroll
  for (int hf = 0; hf < 8; ++hf) {
    int hb = hf * 16 + lg * 4;
    accm[0][hf] = cvt4(ZN + (size_t)n0 * 256 + hb);
    accm[1][hf] = cvt4(ZN + (size_t)n1 * 256 + hb);
    accg[0][hf] = cvt4(ZN + (size_t)n0 * 256 + 128 + hb);
    accg[1][hf] = cvt4(ZN + (size_t)n1 * 256 + 128 + hb);
  }
#pragma unroll
  for (int kc = 0; kc < 4; ++kc) {
    bf16x8 x0 = *(const bf16x8*)(agg + (size_t)n0 * 128 + kc * 32 + lg * 8);
    bf16x8 x1 = *(const bf16x8*)(agg + (size_t)n1 * 128 + kc * 32 + lg * 8);
#pragma unroll
    for (int hf = 0; hf < 8; ++hf) {
      bf16x8 am = ldw(sm, hf * 16 + lr, kc, lg);
      bf16x8 ag = ldw(sm, 128 + hf * 16 + lr, kc, lg);
      accm[0][hf] = MFMA16(am, x0, accm[0][hf]);
      accm[1][hf] = MFMA16(am, x1, accm[1][hf]);
      accg[0][hf] = MFMA16(ag, x0, accg[0][hf]);
      accg[1][hf] = MFMA16(ag, x1, accg[1][hf]);
    }
  }

  f32x4 acc2m[2][8] = {};
  layer2(accm, acc2m, sm + 65536, 0, scr, lg, lr);
  f32x4 acc2g[2][8] = {};
  layer2(accg, acc2g, sm + 65536, 128, scr, lg, lr);

#pragma unroll
  for (int et = 0; et < 2; ++et) {
    float v[8][4];
    float s = 0.f, ss = 0.f;
#pragma unroll
    for (int hf2 = 0; hf2 < 8; ++hf2) {
      float4 b1m = *(const float4*)(sm + 131072 + (hf2 * 16 + lg * 4) * 4);
      float4 b1g = *(const float4*)(sm + 131584 + (hf2 * 16 + lg * 4) * 4);
      f32x4 m = acc2m[et][hf2], g = acc2g[et][hf2];
      v[hf2][0] = (m[0] + b1m.x) * sigm(g[0] + b1g.x);
      v[hf2][1] = (m[1] + b1m.y) * sigm(g[1] + b1g.y);
      v[hf2][2] = (m[2] + b1m.z) * sigm(g[2] + b1g.z);
      v[hf2][3] = (m[3] + b1m.w) * sigm(g[3] + b1g.w);
#pragma unroll
      for (int r = 0; r < 4; ++r) { s += v[hf2][r]; ss += v[hf2][r] * v[hf2][r]; }
    }
    s += __shfl_xor(s, 16, 64);  ss += __shfl_xor(ss, 16, 64);
    s += __shfl_xor(s, 32, 64);  ss += __shfl_xor(ss, 32, 64);
    float mu = s * 0.0078125f;
    float var = ss * 0.0078125f - mu * mu;
    float rs = rsqrtf(var + 1e-5f);
    int n = tb + et * 16 + lr;
    if (n < NN) {
#pragma unroll
      for (int hf2 = 0; hf2 < 8; ++hf2) {
        float4 gm = *(const float4*)(sm + 132096 + (hf2 * 16 + lg * 4) * 4);
        float4 bt = *(const float4*)(sm + 132608 + (hf2 * 16 + lg * 4) * 4);
        float4 o;
        o.x = (v[hf2][0] - mu) * rs * gm.x + bt.x;
        o.y = (v[hf2][1] - mu) * rs * gm.y + bt.y;
        o.z = (v[hf2][2] - mu) * rs * gm.z + bt.z;
        o.w = (v[hf2][3] - mu) * rs * gm.w + bt.w;
        *(float4*)(out + (size_t)n * 128 + hf2 * 16 + lg * 4) = o;
      }
    }
  }
}

extern "C" void kernel_launch(void* const* d_in, const int* in_sizes, int n_in,
                              void* d_out, int out_size, void* d_ws, size_t ws_size,
                              hipStream_t stream) {
  const float* node_inp = (const float*)d_in[0];
  const float* edge_feat = (const float*)d_in[1];
  const float* gstate = (const float*)d_in[2];
  const float* coords = (const float*)d_in[4];
  const int* edge_index = (const int*)d_in[5];
  const float* bWm0 = (const float*)d_in[6];  const float* bbm0 = (const float*)d_in[7];
  const float* bWm1 = (const float*)d_in[8];  const float* bbm1 = (const float*)d_in[9];
  const float* bWg0 = (const float*)d_in[10]; const float* bbg0 = (const float*)d_in[11];
  const float* bWg1 = (const float*)d_in[12]; const float* bbg1 = (const float*)d_in[13];
  const float* nWm0 = (const float*)d_in[14]; const float* nbm0 = (const float*)d_in[15];
  const float* nWm1 = (const float*)d_in[16]; const float* nbm1 = (const float*)d_in[17];
  const float* nWg0 = (const float*)d_in[18]; const float* nbg0 = (const float*)d_in[19];
  const float* nWg1 = (const float*)d_in[20]; const float* nbg1 = (const float*)d_in[21];
  const float* gamma = (const float*)d_in[22]; const float* beta = (const float*)d_in[23];

  char* ws = (char*)d_ws;
  size_t o = 0;
  auto alloc = [&](size_t bytes) {
    size_t r = o; o = (o + bytes + 255) & ~(size_t)255; return r;
  };
  unsigned short* QS   = (unsigned short*)(ws + alloc((size_t)NN * 256 * 2)); // 25.6MB
  int* offsets         = (int*)(ws + alloc((size_t)(NN + 1) * 4));
  int* slotOf          = (int*)(ws + alloc((size_t)NE * 4));
  unsigned short* bondW0eT = (unsigned short*)(ws + alloc(256 * 128 * 2));
  unsigned short* bondW1T  = (unsigned short*)(ws + alloc(256 * 128 * 2));
  unsigned short* pqPW     = (unsigned short*)(ws + alloc(256 * 128 * 2));
  unsigned short* pqQW     = (unsigned short*)(ws + alloc(256 * 128 * 2));
  unsigned short* znW      = (unsigned short*)(ws + alloc(256 * 288 * 2));
  unsigned short* nodeWaggT = (unsigned short*)(ws + alloc(256 * 128 * 2));
  unsigned short* nodeW1T   = (unsigned short*)(ws + alloc(256 * 128 * 2));
  char* concatR        = ws + alloc((size_t)NE * 128 * 2);                   // 204.8MB
  // overlays (lifetime-disjoint):
  unsigned short* PS  = (unsigned short*)d_out;         // dead before node_v4 writes out
  unsigned short* agg = QS;                              // written after bond (QS dead)
  int* cnt    = (int*)concatR;                           // pre-bond
  int* cursor = (int*)(concatR + 262144);                // pre-bond
  unsigned short* ZN = (unsigned short*)(concatR + 1048576);  // written after agg
  unsigned short* concat = (unsigned short*)concatR;

  hipMemsetAsync(cnt, 0, (size_t)NN * 4, stream);

  // weight packs
  pack_seg<<<64, 256, 0, stream>>>(bWm0, 256, 128, bondW0eT, 0, 128);
  pack_seg<<<64, 256, 0, stream>>>(bWg0, 256, 128, bondW0eT, 128, 128);
  pack_seg<<<64, 256, 0, stream>>>(bWm1, 0, 128, bondW1T, 0, 128);
  pack_seg<<<64, 256, 0, stream>>>(bWg1, 0, 128, bondW1T, 128, 128);
  pack_seg<<<64, 256, 0, stream>>>(bWm0, 0, 128, pqPW, 0, 128);
  pack_seg<<<64, 256, 0, stream>>>(bWg0, 0, 128, pqPW, 128, 128);
  pack_seg<<<64, 256, 0, stream>>>(bWm0, 128, 128, pqQW, 0, 128);
  pack_seg<<<64, 256, 0, stream>>>(bWg0, 128, 128, pqQW, 128, 128);
  znpack<<<288, 256, 0, stream>>>(nWm0, nWg0, znW);
  pack_seg<<<64, 256, 0, stream>>>(nWm0, 128, 128, nodeWaggT, 0, 128);
  pack_seg<<<64, 256, 0, stream>>>(nWg0, 128, 128, nodeWaggT, 128, 128);
  pack_seg<<<64, 256, 0, stream>>>(nWm1, 0, 128, nodeW1T, 0, 128);
  pack_seg<<<64, 256, 0, stream>>>(nWg1, 0, 128, nodeW1T, 128, 128);

  // CSR slots
  hist_kernel<<<NE / 256, 256, 0, stream>>>(edge_index, cnt);
  scan1<<<NPART, 256, 0, stream>>>(cnt, (int*)(concatR + 524288));
  scan2<<<1, 256, 0, stream>>>((int*)(concatR + 524288), offsets);
  scan3<<<NPART, 256, 0, stream>>>(cnt, (int*)(concatR + 524288), offsets, cursor);
  fill_kernel<<<NE / 256, 256, 0, stream>>>(edge_index, cursor, slotOf);

  // PS/QS tables
  pq_kernel<<<196, 512, 0, stream>>>(node_inp, pqPW, pqQW, bbm0, bbg0, PS, QS);

  // bond
  bond_v4<<<256, 512, 0, stream>>>(edge_feat, edge_index, slotOf, bondW0eT, bondW1T,
                                   PS, QS, bbm1, bbg1, concat);

  // segment mean (QS dead -> agg overlays it)
  agg_kernel<<<(NN + 3) / 4, 256, 0, stream>>>(offsets, concat, agg);

  // Znode (concat dead -> ZN overlays it)
  zn_kernel<<<196, 512, 0, stream>>>(node_inp, coords, gstate, znW, nbm0, nbg0, ZN);

  // node + LayerNorm -> d_out (PS dead)
  node_v4<<<196, 512, 0, stream>>>(agg, ZN, nodeWaggT, nodeW1T,
                                   nbm1, nbg1, gamma, beta, (float*)d_out);
}